// Round 6
// baseline (568.324 us; speedup 1.0000x reference)
//
#include <hip/hip_runtime.h>
#include <math.h>

// Problem constants (from reference)
#define BATCH 64
#define TDIM 512
#define FEAT 2048
#define HID 1024
#define KDIM 512
#define MROWS (BATCH * TDIM)  // 32768 flat feats rows
#define TCH 16                // k4 time-chunks
#define TCLEN (TDIM / TCH)    // 32 t per chunk

#define NSTEP (FEAT / 64)     // 32 K-tiles (BK=64)
#define TSLOT 1024            // 16B slots per 128x64 bf16 tile
#define ASLOTS (256 * 32 * TSLOT)  // 8,388,608 slots in packed A (128 MiB)
#define BSLOTS (4 * 32 * TSLOT)    // 131,072 slots in packed B (2 MiB)

typedef __attribute__((ext_vector_type(8))) short short8;
typedef __attribute__((ext_vector_type(4))) float floatx4;

// global -> LDS direct DMA, 16B per lane; LDS dest is wave-uniform base,
// lane i lands at base + i*16. Global source IS per-lane.
#define GLL16(g, l)                                                     \
    __builtin_amdgcn_global_load_lds(                                   \
        (const __attribute__((address_space(1))) void*)(g),             \
        (__attribute__((address_space(3))) void*)(l), 16, 0, 0)

// ---------------------------------------------------------------------------
// f32 -> bf16 (round-to-nearest-even)
// ---------------------------------------------------------------------------
__device__ __forceinline__ unsigned short f2bf(float x) {
    unsigned int u = __float_as_uint(x);
    u += 0x7FFFu + ((u >> 16) & 1u);
    return (unsigned short)(u >> 16);
}

// ---------------------------------------------------------------------------
// k0p: blocks [0,8192): pack feats f32 -> bf16, layout [strip128 0..255]
//        [tile 0..31][slot 1024]; slot s holds row r=s>>3 (0..127), logical
//        chunk c=(s&7)^(r&7): feats[strip*128+r][tile*64+c*8 .. +8].
//      blocks [8192,8704): pack U -> [kb 0..3][tile 0..31][slot 1024].
//      blocks [8704,8832): zero the attn-out region (atomicAdd target).
//      blocks [8832,17024): Whb[b,k] = hidden[b]·W[k] + bias[k].
// ---------------------------------------------------------------------------
__global__ __launch_bounds__(256) void k0p(const float* __restrict__ feats,
                                           const float* __restrict__ U,
                                           const float* __restrict__ hidden,
                                           const float* __restrict__ W,
                                           const float* __restrict__ bias,
                                           unsigned short* __restrict__ Apk,
                                           unsigned short* __restrict__ Bpk,
                                           float* __restrict__ whb,
                                           float* __restrict__ attn_zero) {
    int bx = blockIdx.x;
    if (bx < 8192) {
        for (size_t gsl = (size_t)bx * 256 + threadIdx.x; gsl < ASLOTS;
             gsl += (size_t)8192 * 256) {
            int strip = (int)(gsl >> 15);        // 32768 slots per strip
            int rem   = (int)(gsl & 32767);
            int tile  = rem >> 10;
            int s     = rem & 1023;
            int r     = s >> 3;
            int c     = (s & 7) ^ (r & 7);
            const float* src = feats + ((size_t)strip * 128 + r) * FEAT + tile * 64 + c * 8;
            float4 v0 = *(const float4*)src;
            float4 v1 = *(const float4*)(src + 4);
            ushort4 o0, o1;
            o0.x = f2bf(v0.x); o0.y = f2bf(v0.y); o0.z = f2bf(v0.z); o0.w = f2bf(v0.w);
            o1.x = f2bf(v1.x); o1.y = f2bf(v1.y); o1.z = f2bf(v1.z); o1.w = f2bf(v1.w);
            ((ushort4*)Apk)[gsl * 2]     = o0;
            ((ushort4*)Apk)[gsl * 2 + 1] = o1;
        }
    } else if (bx < 8704) {
        size_t gsl = (size_t)(bx - 8192) * 256 + threadIdx.x;  // exactly BSLOTS
        int kb   = (int)(gsl >> 15);
        int rem  = (int)(gsl & 32767);
        int tile = rem >> 10;
        int s    = rem & 1023;
        int r    = s >> 3;
        int c    = (s & 7) ^ (r & 7);
        const float* src = U + ((size_t)kb * 128 + r) * FEAT + tile * 64 + c * 8;
        float4 v0 = *(const float4*)src;
        float4 v1 = *(const float4*)(src + 4);
        ushort4 o0, o1;
        o0.x = f2bf(v0.x); o0.y = f2bf(v0.y); o0.z = f2bf(v0.z); o0.w = f2bf(v0.w);
        o1.x = f2bf(v1.x); o1.y = f2bf(v1.y); o1.z = f2bf(v1.z); o1.w = f2bf(v1.w);
        ((ushort4*)Bpk)[gsl * 2]     = o0;
        ((ushort4*)Bpk)[gsl * 2 + 1] = o1;
    } else if (bx < 8832) {
        int i4 = (bx - 8704) * 256 + threadIdx.x;  // 32768 float4 = B*FEAT
        ((float4*)attn_zero)[i4] = (float4){0.f, 0.f, 0.f, 0.f};
    } else {
        int bid = bx - 8832;                 // 0..8191
        int b = bid >> 7;                    // 0..63
        int k = (bid & 127) * 4 + (threadIdx.x >> 6);
        int lane = threadIdx.x & 63;
        const float* hrow = hidden + (size_t)b * HID;
        const float* wrow = W + (size_t)k * HID;
        float acc = 0.f;
        #pragma unroll 4
        for (int h = lane; h < HID; h += 64) acc += hrow[h] * wrow[h];
        #pragma unroll
        for (int off = 32; off > 0; off >>= 1) acc += __shfl_down(acc, off, 64);
        if (lane == 0) whb[b * KDIM + k] = acc + bias[k];
    }
}

// ---------------------------------------------------------------------------
// k2m: m97-faithful 128x128 bf16 MFMA GEMM + fused tanh/dot(w) epilogue.
// 256 thr = 4 waves (2x2), wave-tile 64x64 -> acc[4][4] f32x4 (64 AGPR).
// Single-buffered 32 KB LDS, plain __syncthreads (compiler inserts waits),
// GLL16 w=16 from the packed buffers (every instr = contiguous 1 KB burst).
// Grid (256 m-blocks, 4 k-blocks) = 1024 blocks ~= 3-4/CU: block-level TLP
// covers the barrier drain (m97/m114 regime, 874-912 TF measured). Blocks
// sharing an A-strip (ids differ by 256 = 0 mod 8) land on the same XCD ->
// A re-read across k-blocks is L2/L3-resident.
// ---------------------------------------------------------------------------
__global__ __launch_bounds__(256) void k2m(const unsigned short* __restrict__ Apk,
                                           const unsigned short* __restrict__ Bpk,
                                           const float* __restrict__ whb,
                                           const float* __restrict__ wvec,
                                           float* __restrict__ partial) {
    __shared__ __align__(16) unsigned short As[TSLOT * 8];  // 16 KB
    __shared__ __align__(16) unsigned short Bs[TSLOT * 8];  // 16 KB

    const int tid  = threadIdx.x;
    const int wave = tid >> 6;
    const int lane = tid & 63;
    const int wm = wave >> 1, wn = wave & 1;
    const int col = lane & 15, quad = lane >> 4;
    const int bx = blockIdx.x;   // 0..255 (m-strip)
    const int kb = blockIdx.y;   // 0..3  (k-block)

    const unsigned short* gA = Apk + ((size_t)bx * (32 * TSLOT) + wave * 256 + lane) * 8;
    const unsigned short* gB = Bpk + ((size_t)kb * (32 * TSLOT) + wave * 256 + lane) * 8;
    unsigned short* lA = As + (wave * 256) * 8;
    unsigned short* lB = Bs + (wave * 256) * 8;

    floatx4 acc[4][4];
    #pragma unroll
    for (int i = 0; i < 4; ++i)
        #pragma unroll
        for (int j = 0; j < 4; ++j) acc[i][j] = (floatx4){0.f, 0.f, 0.f, 0.f};

    for (int t = 0; t < NSTEP; ++t) {
        #pragma unroll
        for (int g = 0; g < 4; ++g) {
            GLL16(gA + (size_t)(t * 1024 + g * 64) * 8, lA + g * 64 * 8);
            GLL16(gB + (size_t)(t * 1024 + g * 64) * 8, lB + g * 64 * 8);
        }
        __syncthreads();

        #pragma unroll
        for (int kk = 0; kk < 2; ++kk) {
            const int sw = (kk * 4 + quad) ^ (col & 7);
            short8 af[4], bf[4];
            #pragma unroll
            for (int i = 0; i < 4; ++i)
                af[i] = *(const short8*)&As[((wm * 64 + i * 16 + col) * 8 + sw) * 8];
            #pragma unroll
            for (int j = 0; j < 4; ++j)
                bf[j] = *(const short8*)&Bs[((wn * 64 + j * 16 + col) * 8 + sw) * 8];
            #pragma unroll
            for (int i = 0; i < 4; ++i)
                #pragma unroll
                for (int j = 0; j < 4; ++j)
                    acc[i][j] = __builtin_amdgcn_mfma_f32_16x16x32_bf16(
                        af[i], bf[j], acc[i][j], 0, 0, 0);
        }
        __syncthreads();
    }

    // Epilogue. C/D layout: col = lane&15 (k-dim), row = quad*4 + reg (m).
    float (*sums)[128] = (float (*)[128])As;  // alias dead As (1 KB)
    const int b = bx >> 2;  // 128-row block = quarter batch (T=512)
    float wk[4], hk[4];
    #pragma unroll
    for (int j = 0; j < 4; ++j) {
        const int k = kb * 128 + wn * 64 + j * 16 + col;
        wk[j] = wvec[k];
        hk[j] = whb[b * KDIM + k];
    }
    #pragma unroll
    for (int i = 0; i < 4; ++i) {
        #pragma unroll
        for (int r = 0; r < 4; ++r) {
            float s = 0.f;
            #pragma unroll
            for (int j = 0; j < 4; ++j)
                s += tanhf(acc[i][j][r] + hk[j]) * wk[j];
            #pragma unroll
            for (int off = 8; off > 0; off >>= 1)
                s += __shfl_down(s, off, 16);
            if (col == 0)
                sums[wn][wm * 64 + i * 16 + quad * 4 + r] = s;
        }
    }
    __syncthreads();
    if (tid < 128)
        partial[(size_t)kb * MROWS + bx * 128 + tid] =
            sums[0][tid] + sums[1][tid];
}

// ---------------------------------------------------------------------------
// k3n: energies = sum of 4 k-block partials (in ws); softmax over T per batch
// ---------------------------------------------------------------------------
__global__ __launch_bounds__(512) void k3n(const float* __restrict__ partial,
                                           float* __restrict__ wout) {
    int b = blockIdx.x;
    int t = threadIdx.x;
    int idx = b * TDIM + t;
    float e = partial[idx] + partial[MROWS + idx] +
              partial[2 * MROWS + idx] + partial[3 * MROWS + idx];

    __shared__ float sm[512];
    sm[t] = e;
    __syncthreads();
    #pragma unroll
    for (int s = 256; s > 0; s >>= 1) {
        if (t < s) sm[t] = fmaxf(sm[t], sm[t + s]);
        __syncthreads();
    }
    float m = sm[0];
    __syncthreads();
    float ex = __expf(e - m);
    sm[t] = ex;
    __syncthreads();
    #pragma unroll
    for (int s = 256; s > 0; s >>= 1) {
        if (t < s) sm[t] += sm[t + s];
        __syncthreads();
    }
    float inv = 1.f / sm[0];
    wout[b * TDIM + t] = ex * inv;
}

// ---------------------------------------------------------------------------
// k4a: T-chunked weighted pooling from the packed bf16 feats, accumulated
// directly into the (pre-zeroed) attn output via atomicAdd (kills k5).
// Thread owns one 8-col chunk: tile=tid>>3, ch=tid&7; row r at phys ch^(r&7).
// ---------------------------------------------------------------------------
__global__ __launch_bounds__(256) void k4a(const unsigned short* __restrict__ Apk,
                                           const float* __restrict__ weights,
                                           float* __restrict__ attn_out) {
    int b  = blockIdx.y;
    int t0 = blockIdx.x * TCLEN;
    int tile = threadIdx.x >> 3;
    int ch   = threadIdx.x & 7;
    int f0   = tile * 64 + ch * 8;
    __shared__ float wsm[TCLEN];
    if (threadIdx.x < TCLEN) wsm[threadIdx.x] = weights[b * TDIM + t0 + threadIdx.x];
    __syncthreads();

    float a[8];
    #pragma unroll
    for (int e = 0; e < 8; ++e) a[e] = 0.f;
    #pragma unroll 4
    for (int t = 0; t < TCLEN; ++t) {
        int row = b * TDIM + t0 + t;
        int strip = row >> 7, r = row & 127;
        const short8 v = *(const short8*)(Apk +
            (((size_t)strip * 32768 + (size_t)tile * TSLOT + r * 8 + (ch ^ (r & 7))) * 8));
        float w = wsm[t];
        #pragma unroll
        for (int e = 0; e < 8; ++e)
            a[e] += __uint_as_float(((unsigned int)(unsigned short)v[e]) << 16) * w;
    }
    float* op = attn_out + (size_t)b * FEAT + f0;
    #pragma unroll
    for (int e = 0; e < 8; ++e) atomicAdd(op + e, a[e]);
}

// ---------------------------------------------------------------------------
// Fallback-path kernels (tiny ws): original k1 + f32 tile GEMM + direct pool
// ---------------------------------------------------------------------------
#define BM 128
#define BN 128
#define BF 16
#define LDSPAD 4

__global__ __launch_bounds__(256) void k1_whb(const float* __restrict__ hidden,
                                              const float* __restrict__ W,
                                              const float* __restrict__ bias,
                                              float* __restrict__ whb) {
    int b = blockIdx.y;
    int k = blockIdx.x * 4 + (threadIdx.x >> 6);
    int lane = threadIdx.x & 63;
    const float* hrow = hidden + (size_t)b * HID;
    const float* wrow = W + (size_t)k * HID;
    float acc = 0.f;
    #pragma unroll 4
    for (int h = lane; h < HID; h += 64) acc += hrow[h] * wrow[h];
    #pragma unroll
    for (int off = 32; off > 0; off >>= 1) acc += __shfl_down(acc, off, 64);
    if (lane == 0) whb[b * KDIM + k] = acc + bias[k];
}

__global__ __launch_bounds__(256) void k2_energy(const float* __restrict__ feats,
                                                 const float* __restrict__ U,
                                                 const float* __restrict__ whb,
                                                 const float* __restrict__ wvec,
                                                 float* __restrict__ partial) {
    __shared__ __align__(16) float As[BF][BM + LDSPAD];
    __shared__ __align__(16) float Us[BF][BN + LDSPAD];

    const int row0 = blockIdx.x * BM;
    const int k0   = blockIdx.y * BN;
    const int tid  = threadIdx.x;
    const int tx   = tid & 15;
    const int ty   = tid >> 4;

    float acc[8][8];
    #pragma unroll
    for (int i = 0; i < 8; ++i)
        #pragma unroll
        for (int j = 0; j < 8; ++j) acc[i][j] = 0.f;

    for (int f0 = 0; f0 < FEAT; f0 += BF) {
        #pragma unroll
        for (int l = 0; l < 2; ++l) {
            int li = tid + l * 256;
            int r  = li >> 2;
            int c4 = (li & 3) * 4;
            float4 av = *(const float4*)(feats + (size_t)(row0 + r) * FEAT + f0 + c4);
            float4 uv = *(const float4*)(U     + (size_t)(k0   + r) * FEAT + f0 + c4);
            As[c4 + 0][r] = av.x; As[c4 + 1][r] = av.y;
            As[c4 + 2][r] = av.z; As[c4 + 3][r] = av.w;
            Us[c4 + 0][r] = uv.x; Us[c4 + 1][r] = uv.y;
            Us[c4 + 2][r] = uv.z; Us[c4 + 3][r] = uv.w;
        }
        __syncthreads();
        #pragma unroll
        for (int kf = 0; kf < BF; ++kf) {
            float4 a0 = *(const float4*)&As[kf][ty * 8];
            float4 a1 = *(const float4*)&As[kf][ty * 8 + 4];
            float4 u0 = *(const float4*)&Us[kf][tx * 8];
            float4 u1 = *(const float4*)&Us[kf][tx * 8 + 4];
            float a[8] = {a0.x, a0.y, a0.z, a0.w, a1.x, a1.y, a1.z, a1.w};
            float u[8] = {u0.x, u0.y, u0.z, u0.w, u1.x, u1.y, u1.z, u1.w};
            #pragma unroll
            for (int i = 0; i < 8; ++i)
                #pragma unroll
                for (int j = 0; j < 8; ++j) acc[i][j] += a[i] * u[j];
        }
        __syncthreads();
    }

    const int b = row0 >> 9;
    float psum[8];
    #pragma unroll
    for (int i = 0; i < 8; ++i) {
        float s = 0.f;
        #pragma unroll
        for (int j = 0; j < 8; ++j) {
            int k = k0 + tx * 8 + j;
            s += tanhf(acc[i][j] + whb[b * KDIM + k]) * wvec[k];
        }
        psum[i] = s;
    }
    #pragma unroll
    for (int off = 8; off > 0; off >>= 1)
        #pragma unroll
        for (int i = 0; i < 8; ++i) psum[i] += __shfl_down(psum[i], off, 16);

    if (tx == 0) {
        int c = blockIdx.y;
        #pragma unroll
        for (int i = 0; i < 8; ++i)
            partial[c * MROWS + row0 + ty * 8 + i] = psum[i];
    }
}

__global__ __launch_bounds__(512) void k3_softmax(const float* __restrict__ partial,
                                                  float* __restrict__ wout) {
    int b = blockIdx.x;
    int t = threadIdx.x;
    float e = 0.f;
    #pragma unroll
    for (int c = 0; c < 4; ++c) e += partial[c * MROWS + b * TDIM + t];

    __shared__ float sm[512];
    sm[t] = e;
    __syncthreads();
    #pragma unroll
    for (int s = 256; s > 0; s >>= 1) {
        if (t < s) sm[t] = fmaxf(sm[t], sm[t + s]);
        __syncthreads();
    }
    float m = sm[0];
    __syncthreads();
    float ex = __expf(e - m);
    sm[t] = ex;
    __syncthreads();
    #pragma unroll
    for (int s = 256; s > 0; s >>= 1) {
        if (t < s) sm[t] += sm[t + s];
        __syncthreads();
    }
    float inv = 1.f / sm[0];
    wout[b * TDIM + t] = ex * inv;
}

__global__ __launch_bounds__(256) void k4_direct(const float* __restrict__ feats,
                                                 const float* __restrict__ weights,
                                                 float* __restrict__ out) {
    int b = blockIdx.y;
    int f4 = (blockIdx.x * 256 + threadIdx.x) * 4;
    __shared__ float wsm[TDIM];
    wsm[threadIdx.x]       = weights[b * TDIM + threadIdx.x];
    wsm[threadIdx.x + 256] = weights[b * TDIM + 256 + threadIdx.x];
    __syncthreads();

    const float* fp = feats + (size_t)b * TDIM * FEAT + f4;
    float ax = 0.f, ay = 0.f, az = 0.f, aw = 0.f;
    for (int t = 0; t < TDIM; ++t) {
        float4 v = *(const float4*)(fp + (size_t)t * FEAT);
        float w = wsm[t];
        ax += v.x * w; ay += v.y * w; az += v.z * w; aw += v.w * w;
    }
    float4 o = {ax, ay, az, aw};
    *(float4*)(out + (size_t)b * FEAT + f4) = o;
}

// ---------------------------------------------------------------------------
// Launch. d_out: [0, B*FEAT) attn_feats (zeroed in k0p, atomic-accumulated
// in k4a), [B*FEAT, +B*T) weights (holds Whb until k2m consumes it).
// d_ws: packed bf16 A (128 MiB) + packed bf16 B (2 MiB) + GEMM partials
// (512 KB). Branch on host-constant ws_size (graph-safe).
// ---------------------------------------------------------------------------
extern "C" void kernel_launch(void* const* d_in, const int* in_sizes, int n_in,
                              void* d_out, int out_size, void* d_ws, size_t ws_size,
                              hipStream_t stream) {
    const float* hidden = (const float*)d_in[0];
    const float* feats  = (const float*)d_in[1];
    const float* W      = (const float*)d_in[2];
    const float* U      = (const float*)d_in[3];
    const float* bias   = (const float*)d_in[4];
    const float* wvec   = (const float*)d_in[5];

    float* out         = (float*)d_out;
    float* attn_out    = out;
    float* weights_out = out + (size_t)BATCH * FEAT;
    float* whb         = weights_out;  // staged (dead after k2m)

    const size_t aBytes    = (size_t)ASLOTS * 16;  // 128 MiB
    const size_t bBytes    = (size_t)BSLOTS * 16;  // 2 MiB
    const size_t pBytes    = (size_t)4 * MROWS * sizeof(float);  // 512 KiB
    const bool fast = ws_size >= aBytes + bBytes + pBytes;

    if (fast) {
        unsigned short* Apk = (unsigned short*)d_ws;
        unsigned short* Bpk = (unsigned short*)((char*)d_ws + aBytes);
        float* partial = (float*)((char*)d_ws + aBytes + bBytes);
        k0p<<<dim3(17024), 256, 0, stream>>>(feats, U, hidden, W, bias,
                                             Apk, Bpk, whb, attn_out);
        k2m<<<dim3(256, 4), 256, 0, stream>>>(Apk, Bpk, whb, wvec, partial);
        k3n<<<dim3(BATCH), 512, 0, stream>>>(partial, weights_out);
        k4a<<<dim3(TCH, BATCH), 256, 0, stream>>>(Apk, weights_out, attn_out);
    } else {
        float* partial = attn_out;
        k1_whb<<<dim3(KDIM / 4, BATCH), 256, 0, stream>>>(hidden, W, bias, whb);
        k2_energy<<<dim3(MROWS / 128, KDIM / 128), 256, 0, stream>>>(
            feats, U, whb, wvec, partial);
        k3_softmax<<<dim3(BATCH), 512, 0, stream>>>(partial, weights_out);
        k4_direct<<<dim3(FEAT / 1024, BATCH), 256, 0, stream>>>(
            feats, weights_out, attn_out);
    }
}